// Round 8
// baseline (716.303 us; speedup 1.0000x reference)
//
#include <hip/hip_runtime.h>
#include <hip/hip_bf16.h>

#define N_NODES 100000
#define N_EDGES 1600000
#define F_IN 165
#define KP0 192    // F_IN padded to multiple of 32
#define HID 128
#define NP2 100096 // slice row stride (>= N, 64-aligned)

#define NBKT 196   // ceil(N/512) coarse dst buckets (dst>>9)
#define EPB1 8192  // edges per block in coarse passes
#define NBLK1 196  // ceil(E/EPB1)
#define NPC 16     // nodes per block in slice aggregate

typedef __attribute__((ext_vector_type(8))) short bf16x8;
typedef __attribute__((ext_vector_type(4))) float f32x4;

__device__ __forceinline__ ushort f2bf(float f) {
    unsigned u = __float_as_uint(f);
    unsigned r = (u + 0x7fffu + ((u >> 16) & 1u)) >> 16;  // RNE
    return (ushort)r;
}
__device__ __forceinline__ float bflo(unsigned p) { return __uint_as_float(p << 16); }
__device__ __forceinline__ float bfhi(unsigned p) { return __uint_as_float(p & 0xffff0000u); }

// ---------------- CSR build via 2-level counting sort ----------------

__global__ __launch_bounds__(256) void k_p1(const int* __restrict__ dst, int* __restrict__ counts, int E) {
    __shared__ int h[NBKT];
    int t = threadIdx.x;
    for (int i = t; i < NBKT; i += 256) h[i] = 0;
    __syncthreads();
    int base = blockIdx.x * EPB1;
    for (int i = 0; i < EPB1; i += 256) {
        int e = base + i + t;
        if (e < E) atomicAdd(&h[dst[e] >> 9], 1);
    }
    __syncthreads();
    for (int i = t; i < NBKT; i += 256) counts[blockIdx.x * NBKT + i] = h[i];
}

__global__ __launch_bounds__(256) void k_p2(const int* __restrict__ counts, int* __restrict__ offs,
                                            int* __restrict__ bbase, int* __restrict__ rowptr, int E) {
    __shared__ int s[256];
    int t = threadIdx.x;
    int tot = 0;
    if (t < NBKT) {
        for (int blk = 0; blk < NBLK1; blk++) tot += counts[blk * NBKT + t];
    }
    s[t] = (t < NBKT) ? tot : 0;
    __syncthreads();
    for (int off = 1; off < 256; off <<= 1) {
        int v = (t >= off) ? s[t - off] : 0;
        __syncthreads();
        s[t] += v;
        __syncthreads();
    }
    int base = s[t] - tot;  // exclusive
    if (t < NBKT) {
        bbase[t] = base;
        int run = base;
        for (int blk = 0; blk < NBLK1; blk++) {
            int c = counts[blk * NBKT + t];
            offs[blk * NBKT + t] = run;
            run += c;
        }
    }
    if (t == 0) rowptr[N_NODES] = E;
}

__global__ __launch_bounds__(256) void k_p3(const int* __restrict__ src, const int* __restrict__ dst,
                                            const int* __restrict__ offs, int* __restrict__ ebuf, int E) {
    __shared__ int cur[NBKT];
    int t = threadIdx.x;
    for (int i = t; i < NBKT; i += 256) cur[i] = offs[blockIdx.x * NBKT + i];
    __syncthreads();
    int base = blockIdx.x * EPB1;
    for (int i = 0; i < EPB1; i += 256) {
        int e = base + i + t;
        if (e < E) {
            int d = dst[e], sv = src[e];
            int pos = atomicAdd(&cur[d >> 9], 1);
            ebuf[pos] = sv | ((d & 511) << 17);
        }
    }
}

__global__ __launch_bounds__(256) void k_p4(const int* __restrict__ ebuf, const int* __restrict__ bbase,
                                            int* __restrict__ rowptr, int* __restrict__ esrc, int E, int N) {
    __shared__ int fh[512], fex[512], fcur[512];
    __shared__ int sc[256];
    int t = threadIdx.x;
    int b = blockIdx.x;
    int base = bbase[b];
    int end = (b + 1 < NBKT) ? bbase[b + 1] : E;
    int cnt = end - base;
    fh[t] = 0; fh[t + 256] = 0; fcur[t] = 0; fcur[t + 256] = 0;
    __syncthreads();
    for (int i = t; i < cnt; i += 256) atomicAdd(&fh[(ebuf[base + i] >> 17) & 511], 1);
    __syncthreads();
    int a0 = fh[2 * t], a1 = fh[2 * t + 1];
    sc[t] = a0 + a1;
    __syncthreads();
    for (int off = 1; off < 256; off <<= 1) {
        int v = (t >= off) ? sc[t - off] : 0;
        __syncthreads();
        sc[t] += v;
        __syncthreads();
    }
    int ex = sc[t] - (a0 + a1);
    fex[2 * t] = ex;
    fex[2 * t + 1] = ex + a0;
    __syncthreads();
    int node0 = b << 9;
    for (int f = t; f < 512; f += 256) {
        int node = node0 + f;
        if (node < N) rowptr[node] = base + fex[f];
    }
    for (int i = t; i < cnt; i += 256) {
        int p = ebuf[base + i];
        int f = (p >> 17) & 511;
        int pos = base + fex[f] + atomicAdd(&fcur[f], 1);
        esrc[pos] = p & 0x1ffff;
    }
}

// ---------------- casts ----------------

__global__ __launch_bounds__(256) void k_cast_x(const float* __restrict__ x, ushort* __restrict__ xb, int NP) {
    int idx = blockIdx.x * 256 + threadIdx.x;
    if (idx >= NP * (KP0 / 8)) return;
    int row = idx / (KP0 / 8), j = idx % (KP0 / 8);
    int c0 = j * 8;
    ushort pk[8];
#pragma unroll
    for (int i = 0; i < 8; i++) {
        int c = c0 + i;
        float v = (row < N_NODES && c < F_IN) ? x[(size_t)row * F_IN + c] : 0.f;
        pk[i] = f2bf(v);
    }
    *(uint4*)(xb + (size_t)row * KP0 + c0) = *(uint4*)pk;
}

__global__ __launch_bounds__(256) void k_cast_w0(const float* __restrict__ Wl, const float* __restrict__ Wr,
                                                 short* __restrict__ Wb) {
    int idx = blockIdx.x * 256 + threadIdx.x;
    if (idx >= 256 * KP0) return;
    int row = idx / KP0, col = idx % KP0;
    const float* W = (row < 128) ? Wl : Wr;
    float v = (col < F_IN) ? W[(size_t)(row & 127) * F_IN + col] : 0.f;
    Wb[idx] = (short)f2bf(v);
}

__global__ __launch_bounds__(256) void k_cast_w12(const float* __restrict__ Wl, const float* __restrict__ Wr,
                                                  short* __restrict__ Wb) {
    int idx = blockIdx.x * 256 + threadIdx.x;
    if (idx >= 2 * 256 * HID) return;
    int layer = idx / (256 * HID);
    int rem = idx % (256 * HID);
    int row = rem / HID, col = rem % HID;
    const float* W = (row < 128) ? Wl : Wr;
    float v = W[(size_t)layer * HID * HID + (size_t)(row & 127) * HID + col];
    Wb[idx] = (short)f2bf(v);
}

// ---------------- register-tiled MFMA dual GEMM ----------------
// A bf16 [Mpad][KPV], W bf16 [256][KPV]
// Y (cols 0..127) stored SLICE-MAJOR: Ys[slice][node][16], slice = c>>4
// R (cols 128..255) stored row-major [node][128]
template <int KPV>
__global__ __launch_bounds__(256) void k_gemm_rt(
    const short* __restrict__ A, const short* __restrict__ W,
    ushort* __restrict__ Ys, ushort* __restrict__ Rb, int M)
{
    constexpr int NK = KPV / 32;
    int wave = threadIdx.x >> 6;
    int lane = threadIdx.x & 63;
    int lr = lane & 15;
    int kg = lane >> 4;
    int m0 = blockIdx.x * 64;
    int wc = wave * 64;

    f32x4 acc[4][4];
#pragma unroll
    for (int i = 0; i < 4; i++)
#pragma unroll
        for (int j = 0; j < 4; j++) acc[i][j] = {0.f, 0.f, 0.f, 0.f};

    const short* abase = A + (size_t)(m0 + lr) * KPV + kg * 8;
    const short* wbase = W + (size_t)(wc + lr) * KPV + kg * 8;

#pragma unroll
    for (int ks = 0; ks < NK; ks++) {
        bf16x8 a[4], b[4];
#pragma unroll
        for (int rt = 0; rt < 4; rt++)
            a[rt] = *(const bf16x8*)(abase + (size_t)rt * 16 * KPV + ks * 32);
#pragma unroll
        for (int ntl = 0; ntl < 4; ntl++)
            b[ntl] = *(const bf16x8*)(wbase + (size_t)ntl * 16 * KPV + ks * 32);
#pragma unroll
        for (int rt = 0; rt < 4; rt++)
#pragma unroll
            for (int ntl = 0; ntl < 4; ntl++)
                acc[rt][ntl] = __builtin_amdgcn_mfma_f32_16x16x32_bf16(a[rt], b[ntl], acc[rt][ntl], 0, 0, 0);
    }

#pragma unroll
    for (int rt = 0; rt < 4; rt++) {
#pragma unroll
        for (int ntl = 0; ntl < 4; ntl++) {
            int c = wc + ntl * 16 + lr;
#pragma unroll
            for (int r = 0; r < 4; r++) {
                float v = acc[rt][ntl][r];
                float vp = __shfl_xor(v, 1);
                unsigned pk = (unsigned)f2bf(v) | ((unsigned)f2bf(vp) << 16);
                int node = m0 + rt * 16 + kg * 4 + r;
                if (!(lr & 1) && node < M) {
                    if (c < HID) {
                        int sl = c >> 4, wi = c & 15;
                        *(unsigned*)(Ys + ((size_t)sl * NP2 + node) * 16 + wi) = pk;
                    } else {
                        *(unsigned*)(Rb + (size_t)node * HID + (c - HID)) = pk;
                    }
                }
            }
        }
    }
}

// ---------------- slice-partitioned aggregate (XCD-resident gather) ----------------
// grid = nchunks*8; slice = blockIdx&7 -> lands on one XCD (round-robin dispatch),
// whose Y working set (Ys[slice] = 3.2 MB) fits the 4 MB per-XCD L2.
// 8-lane sub-groups: 8 edges in flight per wave; lane owns 2 features of the slice.
__global__ __launch_bounds__(256) void k_agg_slice(
    const ushort* __restrict__ Ys, const int* __restrict__ rowptr,
    const int* __restrict__ esrc, ushort* __restrict__ Hpre, int N)
{
    int slice = blockIdx.x & 7;
    int chunk = blockIdx.x >> 3;
    int wave = threadIdx.x >> 6, lane = threadIdx.x & 63;
    int g = lane >> 3, fl = lane & 7;
    const ushort* ybase = Ys + (size_t)slice * NP2 * 16 + fl * 2;

    for (int i = 0; i < NPC / 4; i++) {
        int node = chunk * NPC + wave * (NPC / 4) + i;
        if (node >= N) return;
        int beg = rowptr[node], end = rowptr[node + 1];
        float s0 = 0.f, s1 = 0.f;
        for (int c0 = beg; c0 < end; c0 += 64) {
            int e = c0 + lane;
            int idv = (e < end) ? esrc[e] : 0;
            int lim = end - c0; if (lim > 64) lim = 64;
            for (int t = 0; t < lim; t += 16) {  // 2 gathers in flight per wave
                int sid0 = __shfl(idv, (t + g) & 63);
                int sid1 = __shfl(idv, (t + 8 + g) & 63);
                unsigned p0 = *(const unsigned*)(ybase + (size_t)sid0 * 16);
                unsigned p1 = *(const unsigned*)(ybase + (size_t)sid1 * 16);
                float m0 = (t + g < lim) ? 1.f : 0.f;
                float m1 = (t + 8 + g < lim) ? 1.f : 0.f;
                s0 = fmaf(m0, bflo(p0), s0);
                s1 = fmaf(m0, bfhi(p0), s1);
                s0 = fmaf(m1, bflo(p1), s0);
                s1 = fmaf(m1, bfhi(p1), s1);
            }
        }
        s0 += __shfl_xor(s0, 8);  s1 += __shfl_xor(s1, 8);
        s0 += __shfl_xor(s0, 16); s1 += __shfl_xor(s1, 16);
        s0 += __shfl_xor(s0, 32); s1 += __shfl_xor(s1, 32);
        if (lane < 8) {
            unsigned pk = (unsigned)f2bf(s0) | ((unsigned)f2bf(s1) << 16);
            *(unsigned*)(Hpre + (size_t)node * HID + slice * 16 + fl * 2) = pk;
        }
    }
}

// ---------------- finish: mean + bias + root + (residual+LN) + ReLU (+ final proj) ----------------
__global__ __launch_bounds__(256) void k_finish(
    const ushort* __restrict__ Hpre, const ushort* __restrict__ Rm,
    const ushort* __restrict__ Hres, const int* __restrict__ rowptr,
    const float* __restrict__ bias, ushort* __restrict__ HbOut,
    const float* __restrict__ lW, const float* __restrict__ lb,
    float* __restrict__ out, int N, int mode)
{
    int lane = threadIdx.x & 63;
    int node = blockIdx.x * 4 + (threadIdx.x >> 6);
    if (node >= N) return;
    int beg = rowptr[node], end = rowptr[node + 1];
    float inv = 1.0f / fmaxf((float)(end - beg), 1.0f);
    size_t base = (size_t)node * HID;
    unsigned sp = *(const unsigned*)(Hpre + base + 2 * lane);
    float2 b2 = *(const float2*)(bias + 2 * lane);
    unsigned r2 = *(const unsigned*)(Rm + base + 2 * lane);
    float v0 = bflo(sp) * inv + b2.x + bflo(r2);
    float v1 = bfhi(sp) * inv + b2.y + bfhi(r2);
    float o0, o1;
    if (mode == 0) {
        o0 = fmaxf(v0, 0.f);
        o1 = fmaxf(v1, 0.f);
    } else {
        unsigned h2 = *(const unsigned*)(Hres + base + 2 * lane);
        float z0 = v0 + bflo(h2);
        float z1 = v1 + bfhi(h2);
        float sum = z0 + z1;
#pragma unroll
        for (int off = 32; off; off >>= 1) sum += __shfl_xor(sum, off);
        float mu = sum * (1.f / 128.f);
        float d0 = z0 - mu, d1 = z1 - mu;
        float vs = d0 * d0 + d1 * d1;
#pragma unroll
        for (int off = 32; off; off >>= 1) vs += __shfl_xor(vs, off);
        float rstd = rsqrtf(vs * (1.f / 128.f) + 1e-5f);
        o0 = fmaxf(d0 * rstd, 0.f);
        o1 = fmaxf(d1 * rstd, 0.f);
    }
    if (mode == 2) {
        float2 w0 = *(const float2*)(lW + 2 * lane);
        float2 w1 = *(const float2*)(lW + 128 + 2 * lane);
        float p0 = o0 * w0.x + o1 * w0.y;
        float p1 = o0 * w1.x + o1 * w1.y;
#pragma unroll
        for (int off = 32; off; off >>= 1) {
            p0 += __shfl_xor(p0, off);
            p1 += __shfl_xor(p1, off);
        }
        if (lane == 0) {
            out[(size_t)node * 2 + 0] = p0 + lb[0];
            out[(size_t)node * 2 + 1] = p1 + lb[1];
        }
    } else {
        unsigned pk = (unsigned)f2bf(o0) | ((unsigned)f2bf(o1) << 16);
        *(unsigned*)(HbOut + base + 2 * lane) = pk;
    }
}

extern "C" void kernel_launch(void* const* d_in, const int* in_sizes, int n_in,
                              void* d_out, int out_size, void* d_ws, size_t ws_size,
                              hipStream_t stream) {
    const int N = N_NODES, E = N_EDGES;
    const float* x   = (const float*)d_in[0];
    const int*   ei  = (const int*)d_in[1];
    const float* Wl0 = (const float*)d_in[2];
    const float* bl0 = (const float*)d_in[3];
    const float* Wr0 = (const float*)d_in[4];
    const float* Wl  = (const float*)d_in[5];
    const float* bl  = (const float*)d_in[6];
    const float* Wr  = (const float*)d_in[7];
    const float* lW  = (const float*)d_in[8];
    const float* lb  = (const float*)d_in[9];
    float* out = (float*)d_out;

    const int* src = ei;
    const int* dst = ei + E;

    const int PADR = 64;
    const int NP = ((N + 63) / 64) * 64;

    char* w = (char*)d_ws;
    ushort* Ys  = (ushort*)w; w += (size_t)8 * NP2 * 16 * sizeof(ushort);
    ushort* Rb  = (ushort*)w; w += (size_t)(N + PADR) * HID * sizeof(ushort);
    ushort* Hb  = (ushort*)w; w += (size_t)(N + PADR) * HID * sizeof(ushort);
    ushort* Hpre= (ushort*)w; w += (size_t)N * HID * sizeof(ushort);
    ushort* xb  = (ushort*)w; w += (size_t)(N + PADR) * KP0 * sizeof(ushort);
    short*  Wb0 = (short*)w;  w += (size_t)256 * KP0 * sizeof(short);
    short*  Wb12= (short*)w;  w += (size_t)2 * 256 * HID * sizeof(short);
    int* counts = (int*)w;    w += (size_t)NBLK1 * NBKT * sizeof(int);
    int* offs   = (int*)w;    w += (size_t)NBLK1 * NBKT * sizeof(int);
    int* bbase  = (int*)w;    w += (size_t)NBKT * sizeof(int);
    int* rowptr = (int*)w;    w += (size_t)(N + 1) * sizeof(int);
    int* ebuf   = (int*)w;    w += (size_t)E * sizeof(int);
    int* esrc   = (int*)w;    w += (size_t)E * sizeof(int);

    const int nbGemm = (N + 63) / 64;
    const int nbNode = (N + 3) / 4;
    const int nbAgg  = ((N + NPC - 1) / NPC) * 8;

    // CSR build (2-level counting sort)
    k_p1<<<NBLK1, 256, 0, stream>>>(dst, counts, E);
    k_p2<<<1, 256, 0, stream>>>(counts, offs, bbase, rowptr, E);
    k_p3<<<NBLK1, 256, 0, stream>>>(src, dst, offs, ebuf, E);
    k_p4<<<NBKT, 256, 0, stream>>>(ebuf, bbase, rowptr, esrc, E, N);

    // casts
    k_cast_x<<<(NP * (KP0 / 8) + 255) / 256, 256, 0, stream>>>(x, xb, NP);
    k_cast_w0<<<(256 * KP0 + 255) / 256, 256, 0, stream>>>(Wl0, Wr0, Wb0);
    k_cast_w12<<<(2 * 256 * HID + 255) / 256, 256, 0, stream>>>(Wl, Wr, Wb12);

    // layer 0
    k_gemm_rt<KP0><<<nbGemm, 256, 0, stream>>>((const short*)xb, Wb0, Ys, Rb, N);
    k_agg_slice<<<nbAgg, 256, 0, stream>>>(Ys, rowptr, esrc, Hpre, N);
    k_finish<<<nbNode, 256, 0, stream>>>(Hpre, Rb, nullptr, rowptr, bl0, Hb,
                                         nullptr, nullptr, nullptr, N, 0);

    // layer 1
    k_gemm_rt<HID><<<nbGemm, 256, 0, stream>>>((const short*)Hb, Wb12, Ys, Rb, N);
    k_agg_slice<<<nbAgg, 256, 0, stream>>>(Ys, rowptr, esrc, Hpre, N);
    k_finish<<<nbNode, 256, 0, stream>>>(Hpre, Rb, Hb, rowptr, bl, Hb,
                                         nullptr, nullptr, nullptr, N, 1);

    // layer 2 + fused final projection
    k_gemm_rt<HID><<<nbGemm, 256, 0, stream>>>((const short*)Hb, Wb12 + 256 * HID, Ys, Rb, N);
    k_agg_slice<<<nbAgg, 256, 0, stream>>>(Ys, rowptr, esrc, Hpre, N);
    k_finish<<<nbNode, 256, 0, stream>>>(Hpre, Rb, Hb, rowptr, bl + HID, nullptr,
                                         lW, lb, out, N, 2);
}

// Round 9
// 372.866 us; speedup vs baseline: 1.9211x; 1.9211x over previous
//
#include <hip/hip_runtime.h>
#include <hip/hip_bf16.h>

#define N_NODES 100000
#define N_EDGES 1600000
#define F_IN 165
#define KP0 192   // F_IN padded to multiple of 32
#define HID 128

#define NBKT 196   // ceil(N/512) coarse dst buckets (dst>>9)
#define EPB1 8192  // edges per block in coarse passes
#define NBLK1 196  // ceil(E/EPB1)

typedef __attribute__((ext_vector_type(8))) short bf16x8;
typedef __attribute__((ext_vector_type(4))) float f32x4;
typedef __attribute__((ext_vector_type(2))) float f32x2;

__device__ __forceinline__ ushort f2bf(float f) {
    unsigned u = __float_as_uint(f);
    unsigned r = (u + 0x7fffu + ((u >> 16) & 1u)) >> 16;  // RNE
    return (ushort)r;
}
__device__ __forceinline__ float bflo(unsigned p) { return __uint_as_float(p << 16); }
__device__ __forceinline__ float bfhi(unsigned p) { return __uint_as_float(p & 0xffff0000u); }

// ---------------- CSR build via 2-level counting sort ----------------

__global__ __launch_bounds__(256) void k_p1(const int* __restrict__ dst, int* __restrict__ counts, int E) {
    __shared__ int h[NBKT];
    int t = threadIdx.x;
    for (int i = t; i < NBKT; i += 256) h[i] = 0;
    __syncthreads();
    int base = blockIdx.x * EPB1;
    for (int i = 0; i < EPB1; i += 256) {
        int e = base + i + t;
        if (e < E) atomicAdd(&h[dst[e] >> 9], 1);
    }
    __syncthreads();
    for (int i = t; i < NBKT; i += 256) counts[blockIdx.x * NBKT + i] = h[i];
}

__global__ __launch_bounds__(256) void k_p2(const int* __restrict__ counts, int* __restrict__ offs,
                                            int* __restrict__ bbase, int* __restrict__ rowptr, int E) {
    __shared__ int s[256];
    int t = threadIdx.x;
    int tot = 0;
    if (t < NBKT) {
        for (int blk = 0; blk < NBLK1; blk++) tot += counts[blk * NBKT + t];
    }
    s[t] = (t < NBKT) ? tot : 0;
    __syncthreads();
    for (int off = 1; off < 256; off <<= 1) {
        int v = (t >= off) ? s[t - off] : 0;
        __syncthreads();
        s[t] += v;
        __syncthreads();
    }
    int base = s[t] - tot;  // exclusive
    if (t < NBKT) {
        bbase[t] = base;
        int run = base;
        for (int blk = 0; blk < NBLK1; blk++) {
            int c = counts[blk * NBKT + t];
            offs[blk * NBKT + t] = run;
            run += c;
        }
    }
    if (t == 0) rowptr[N_NODES] = E;
}

__global__ __launch_bounds__(256) void k_p3(const int* __restrict__ src, const int* __restrict__ dst,
                                            const int* __restrict__ offs, int* __restrict__ ebuf, int E) {
    __shared__ int cur[NBKT];
    int t = threadIdx.x;
    for (int i = t; i < NBKT; i += 256) cur[i] = offs[blockIdx.x * NBKT + i];
    __syncthreads();
    int base = blockIdx.x * EPB1;
    for (int i = 0; i < EPB1; i += 256) {
        int e = base + i + t;
        if (e < E) {
            int d = dst[e], sv = src[e];
            int pos = atomicAdd(&cur[d >> 9], 1);
            ebuf[pos] = sv | ((d & 511) << 17);
        }
    }
}

__global__ __launch_bounds__(256) void k_p4(const int* __restrict__ ebuf, const int* __restrict__ bbase,
                                            int* __restrict__ rowptr, int* __restrict__ esrc, int E, int N) {
    __shared__ int fh[512], fex[512], fcur[512];
    __shared__ int sc[256];
    int t = threadIdx.x;
    int b = blockIdx.x;
    int base = bbase[b];
    int end = (b + 1 < NBKT) ? bbase[b + 1] : E;
    int cnt = end - base;
    fh[t] = 0; fh[t + 256] = 0; fcur[t] = 0; fcur[t + 256] = 0;
    __syncthreads();
    for (int i = t; i < cnt; i += 256) atomicAdd(&fh[(ebuf[base + i] >> 17) & 511], 1);
    __syncthreads();
    int a0 = fh[2 * t], a1 = fh[2 * t + 1];
    sc[t] = a0 + a1;
    __syncthreads();
    for (int off = 1; off < 256; off <<= 1) {
        int v = (t >= off) ? sc[t - off] : 0;
        __syncthreads();
        sc[t] += v;
        __syncthreads();
    }
    int ex = sc[t] - (a0 + a1);
    fex[2 * t] = ex;
    fex[2 * t + 1] = ex + a0;
    __syncthreads();
    int node0 = b << 9;
    for (int f = t; f < 512; f += 256) {
        int node = node0 + f;
        if (node < N) rowptr[node] = base + fex[f];
    }
    for (int i = t; i < cnt; i += 256) {
        int p = ebuf[base + i];
        int f = (p >> 17) & 511;
        int pos = base + fex[f] + atomicAdd(&fcur[f], 1);
        esrc[pos] = p & 0x1ffff;
    }
}

// ---------------- casts ----------------

__global__ __launch_bounds__(256) void k_cast_x(const float* __restrict__ x, ushort* __restrict__ xb, int NP) {
    int idx = blockIdx.x * 256 + threadIdx.x;
    if (idx >= NP * (KP0 / 8)) return;
    int row = idx / (KP0 / 8), j = idx % (KP0 / 8);
    int c0 = j * 8;
    ushort pk[8];
#pragma unroll
    for (int i = 0; i < 8; i++) {
        int c = c0 + i;
        float v = (row < N_NODES && c < F_IN) ? x[(size_t)row * F_IN + c] : 0.f;
        pk[i] = f2bf(v);
    }
    *(uint4*)(xb + (size_t)row * KP0 + c0) = *(uint4*)pk;
}

// fused weight cast: Wb0 [256][192] then Wb12 [2][256][128]
__global__ __launch_bounds__(256) void k_cast_w(
    const float* __restrict__ Wl0, const float* __restrict__ Wr0,
    const float* __restrict__ Wl, const float* __restrict__ Wr,
    short* __restrict__ Wb0, short* __restrict__ Wb12)
{
    int idx = blockIdx.x * 256 + threadIdx.x;
    if (idx < 256 * KP0) {
        int row = idx / KP0, col = idx % KP0;
        const float* W = (row < 128) ? Wl0 : Wr0;
        float v = (col < F_IN) ? W[(size_t)(row & 127) * F_IN + col] : 0.f;
        Wb0[idx] = (short)f2bf(v);
    } else {
        int i2 = idx - 256 * KP0;
        if (i2 >= 2 * 256 * HID) return;
        int layer = i2 / (256 * HID);
        int rem = i2 % (256 * HID);
        int row = rem / HID, col = rem % HID;
        const float* W = (row < 128) ? Wl : Wr;
        float v = W[(size_t)layer * HID * HID + (size_t)(row & 127) * HID + col];
        Wb12[i2] = (short)f2bf(v);
    }
}

// ---------------- register-tiled MFMA dual GEMM ----------------
// A bf16 [Mpad][KPV], W bf16 [256][KPV]
// Y (cols 0..127) stored fp8 e4m3: Yq[node][128]  (1 B/elem)
// R (cols 128..255) stored bf16 row-major [node][128]
template <int KPV>
__global__ __launch_bounds__(256) void k_gemm_rt(
    const short* __restrict__ A, const short* __restrict__ W,
    unsigned char* __restrict__ Yq, ushort* __restrict__ Rb, int M)
{
    constexpr int NK = KPV / 32;
    int wave = threadIdx.x >> 6;
    int lane = threadIdx.x & 63;
    int lr = lane & 15;
    int kg = lane >> 4;
    int m0 = blockIdx.x * 64;
    int wc = wave * 64;

    f32x4 acc[4][4];
#pragma unroll
    for (int i = 0; i < 4; i++)
#pragma unroll
        for (int j = 0; j < 4; j++) acc[i][j] = {0.f, 0.f, 0.f, 0.f};

    const short* abase = A + (size_t)(m0 + lr) * KPV + kg * 8;
    const short* wbase = W + (size_t)(wc + lr) * KPV + kg * 8;

#pragma unroll
    for (int ks = 0; ks < NK; ks++) {
        bf16x8 a[4], b[4];
#pragma unroll
        for (int rt = 0; rt < 4; rt++)
            a[rt] = *(const bf16x8*)(abase + (size_t)rt * 16 * KPV + ks * 32);
#pragma unroll
        for (int ntl = 0; ntl < 4; ntl++)
            b[ntl] = *(const bf16x8*)(wbase + (size_t)ntl * 16 * KPV + ks * 32);
#pragma unroll
        for (int rt = 0; rt < 4; rt++)
#pragma unroll
            for (int ntl = 0; ntl < 4; ntl++)
                acc[rt][ntl] = __builtin_amdgcn_mfma_f32_16x16x32_bf16(a[rt], b[ntl], acc[rt][ntl], 0, 0, 0);
    }

#pragma unroll
    for (int rt = 0; rt < 4; rt++) {
#pragma unroll
        for (int ntl = 0; ntl < 4; ntl++) {
            int c = wc + ntl * 16 + lr;      // wave-uniform Y/R split (wc 0,64 -> Y; 128,192 -> R)
            bool isY = (c < HID);
#pragma unroll
            for (int r = 0; r < 4; r++) {
                float v = acc[rt][ntl][r];
                float vp = __shfl_xor(v, 1);
                int node = m0 + rt * 16 + kg * 4 + r;
                if (isY) {
                    // bytes (c,c+1) on this lane pair; (c+2,c+3) from partner pair
                    int b01 = __builtin_amdgcn_cvt_pk_fp8_f32(v, vp, 0, false);
                    int b23 = __shfl_xor(b01, 2);
                    if (!(lr & 3) && node < M) {
                        unsigned pk = ((unsigned)b01 & 0xffffu) | ((unsigned)b23 << 16);
                        *(unsigned*)(Yq + (size_t)node * HID + c) = pk;
                    }
                } else {
                    unsigned pk = (unsigned)f2bf(v) | ((unsigned)f2bf(vp) << 16);
                    if (!(lr & 1) && node < M)
                        *(unsigned*)(Rb + (size_t)node * HID + (c - HID)) = pk;
                }
            }
        }
    }
}

// ---------------- fused aggregate + bias + root + (LN) + ReLU (+ final proj) ----------------
// one wave per node; half-wave per edge (32 lanes x 4B = 128 B fp8 row)
// lane owns features 4c..4c+3 (c = lane&31); halves hold duplicate sums after merge
__global__ __launch_bounds__(256) void k_aggregate(
    const unsigned char* __restrict__ Yq, const ushort* __restrict__ Rm,
    const ushort* __restrict__ Hres,
    const int* __restrict__ rowptr, const int* __restrict__ esrc,
    const float* __restrict__ bias, ushort* __restrict__ HbOut,
    const float* __restrict__ lW, const float* __restrict__ lb,
    float* __restrict__ out, int N, int mode)
{
    int lane = threadIdx.x & 63;
    int node = blockIdx.x * 4 + (threadIdx.x >> 6);
    if (node >= N) return;
    int h = lane >> 5;
    int c = lane & 31;
    const unsigned* ybase = (const unsigned*)Yq + c;   // dword index: row*32 + c
    int beg = rowptr[node], end = rowptr[node + 1];
    float s0 = 0.f, s1 = 0.f, s2 = 0.f, s3 = 0.f;
    for (int c0 = beg; c0 < end; c0 += 64) {
        int lim = end - c0; if (lim > 64) lim = 64;
        int idv = (c0 + lane < end) ? esrc[c0 + lane] : 0;
        for (int t = 0; t < lim; t += 8) {   // 8 edges/iter, 4 loads in flight per lane
            unsigned p[4];
#pragma unroll
            for (int u = 0; u < 4; u++) {
                int e = t + 2 * u + h;
                int sid = __shfl(idv, e);
                unsigned q = ybase[(size_t)sid * 32];
                p[u] = (e < lim) ? q : 0u;   // 0x00 decodes to +0.0 in e4m3
            }
#pragma unroll
            for (int u = 0; u < 4; u++) {
                f32x2 lo = __builtin_amdgcn_cvt_pk_f32_fp8((int)p[u], false);
                f32x2 hi = __builtin_amdgcn_cvt_pk_f32_fp8((int)p[u], true);
                s0 += lo[0]; s1 += lo[1]; s2 += hi[0]; s3 += hi[1];
            }
        }
    }
    // merge halves: butterfly gives BOTH halves the full sums
    s0 += __shfl_xor(s0, 32); s1 += __shfl_xor(s1, 32);
    s2 += __shfl_xor(s2, 32); s3 += __shfl_xor(s3, 32);

    float inv = 1.0f / fmaxf((float)(end - beg), 1.0f);
    size_t base = (size_t)node * HID + 4 * c;
    float4 b4 = *(const float4*)(bias + 4 * c);
    uint2 r2 = *(const uint2*)(Rm + base);
    float v0 = s0 * inv + b4.x + bflo(r2.x);
    float v1 = s1 * inv + b4.y + bfhi(r2.x);
    float v2 = s2 * inv + b4.z + bflo(r2.y);
    float v3 = s3 * inv + b4.w + bfhi(r2.y);
    float o0, o1, o2, o3;
    if (mode == 0) {
        o0 = fmaxf(v0, 0.f); o1 = fmaxf(v1, 0.f);
        o2 = fmaxf(v2, 0.f); o3 = fmaxf(v3, 0.f);
    } else {
        uint2 h2 = *(const uint2*)(Hres + base);
        float z0 = v0 + bflo(h2.x), z1 = v1 + bfhi(h2.x);
        float z2 = v2 + bflo(h2.y), z3 = v3 + bfhi(h2.y);
        float sum = z0 + z1 + z2 + z3;                 // every feature counted twice wave-wide
#pragma unroll
        for (int off = 32; off; off >>= 1) sum += __shfl_xor(sum, off);
        float mu = sum * (1.f / 256.f);
        float d0 = z0 - mu, d1 = z1 - mu, d2 = z2 - mu, d3 = z3 - mu;
        float vs = d0 * d0 + d1 * d1 + d2 * d2 + d3 * d3;
#pragma unroll
        for (int off = 32; off; off >>= 1) vs += __shfl_xor(vs, off);
        float rstd = rsqrtf(vs * (1.f / 256.f) + 1e-5f);
        o0 = fmaxf(d0 * rstd, 0.f); o1 = fmaxf(d1 * rstd, 0.f);
        o2 = fmaxf(d2 * rstd, 0.f); o3 = fmaxf(d3 * rstd, 0.f);
    }
    if (mode == 2) {
        float4 w0 = *(const float4*)(lW + 4 * c);
        float4 w1 = *(const float4*)(lW + 128 + 4 * c);
        float p0 = o0 * w0.x + o1 * w0.y + o2 * w0.z + o3 * w0.w;
        float p1 = o0 * w1.x + o1 * w1.y + o2 * w1.z + o3 * w1.w;
#pragma unroll
        for (int off = 32; off; off >>= 1) {
            p0 += __shfl_xor(p0, off);
            p1 += __shfl_xor(p1, off);
        }
        if (lane == 0) {
            out[(size_t)node * 2 + 0] = 0.5f * p0 + lb[0];   // halve the duplicate count
            out[(size_t)node * 2 + 1] = 0.5f * p1 + lb[1];
        }
    } else if (h == 0) {
        unsigned pk0 = (unsigned)f2bf(o0) | ((unsigned)f2bf(o1) << 16);
        unsigned pk1 = (unsigned)f2bf(o2) | ((unsigned)f2bf(o3) << 16);
        uint2 pk; pk.x = pk0; pk.y = pk1;
        *(uint2*)(HbOut + base) = pk;
    }
}

extern "C" void kernel_launch(void* const* d_in, const int* in_sizes, int n_in,
                              void* d_out, int out_size, void* d_ws, size_t ws_size,
                              hipStream_t stream) {
    const int N = N_NODES, E = N_EDGES;
    const float* x   = (const float*)d_in[0];
    const int*   ei  = (const int*)d_in[1];
    const float* Wl0 = (const float*)d_in[2];
    const float* bl0 = (const float*)d_in[3];
    const float* Wr0 = (const float*)d_in[4];
    const float* Wl  = (const float*)d_in[5];
    const float* bl  = (const float*)d_in[6];
    const float* Wr  = (const float*)d_in[7];
    const float* lW  = (const float*)d_in[8];
    const float* lb  = (const float*)d_in[9];
    float* out = (float*)d_out;

    const int* src = ei;
    const int* dst = ei + E;

    const int PADR = 64;
    const int NP = ((N + 63) / 64) * 64;

    char* w = (char*)d_ws;
    unsigned char* Yq = (unsigned char*)w; w += (size_t)(N + PADR) * HID;  // fp8
    ushort* Rb  = (ushort*)w; w += (size_t)(N + PADR) * HID * sizeof(ushort);
    ushort* Hb  = (ushort*)w; w += (size_t)(N + PADR) * HID * sizeof(ushort);
    ushort* xb  = (ushort*)w; w += (size_t)(N + PADR) * KP0 * sizeof(ushort);
    short*  Wb0 = (short*)w;  w += (size_t)256 * KP0 * sizeof(short);
    short*  Wb12= (short*)w;  w += (size_t)2 * 256 * HID * sizeof(short);
    int* counts = (int*)w;    w += (size_t)NBLK1 * NBKT * sizeof(int);
    int* offs   = (int*)w;    w += (size_t)NBLK1 * NBKT * sizeof(int);
    int* bbase  = (int*)w;    w += (size_t)NBKT * sizeof(int);
    int* rowptr = (int*)w;    w += (size_t)(N + 1) * sizeof(int);
    int* ebuf   = (int*)w;    w += (size_t)E * sizeof(int);
    int* esrc   = (int*)w;    w += (size_t)E * sizeof(int);

    const int nbGemm = (N + 63) / 64;
    const int nbNode = (N + 3) / 4;

    // CSR build (2-level counting sort)
    k_p1<<<NBLK1, 256, 0, stream>>>(dst, counts, E);
    k_p2<<<1, 256, 0, stream>>>(counts, offs, bbase, rowptr, E);
    k_p3<<<NBLK1, 256, 0, stream>>>(src, dst, offs, ebuf, E);
    k_p4<<<NBKT, 256, 0, stream>>>(ebuf, bbase, rowptr, esrc, E, N);

    // casts
    k_cast_x<<<(NP * (KP0 / 8) + 255) / 256, 256, 0, stream>>>(x, xb, NP);
    k_cast_w<<<(256 * KP0 + 2 * 256 * HID + 255) / 256, 256, 0, stream>>>(Wl0, Wr0, Wl, Wr, Wb0, Wb12);

    // layer 0
    k_gemm_rt<KP0><<<nbGemm, 256, 0, stream>>>((const short*)xb, Wb0, Yq, Rb, N);
    k_aggregate<<<nbNode, 256, 0, stream>>>(Yq, Rb, nullptr, rowptr, esrc, bl0, Hb,
                                            nullptr, nullptr, nullptr, N, 0);

    // layer 1
    k_gemm_rt<HID><<<nbGemm, 256, 0, stream>>>((const short*)Hb, Wb12, Yq, Rb, N);
    k_aggregate<<<nbNode, 256, 0, stream>>>(Yq, Rb, Hb, rowptr, esrc, bl, Hb,
                                            nullptr, nullptr, nullptr, N, 1);

    // layer 2 + fused final projection
    k_gemm_rt<HID><<<nbGemm, 256, 0, stream>>>((const short*)Hb, Wb12 + 256 * HID, Yq, Rb, N);
    k_aggregate<<<nbNode, 256, 0, stream>>>(Yq, Rb, Hb, rowptr, esrc, bl + HID, nullptr,
                                            lW, lb, out, N, 2);
}

// Round 10
// 371.663 us; speedup vs baseline: 1.9273x; 1.0032x over previous
//
#include <hip/hip_runtime.h>
#include <hip/hip_bf16.h>

#define N_NODES 100000
#define N_EDGES 1600000
#define F_IN 165
#define KP0 192   // F_IN padded to multiple of 32
#define HID 128

#define NBKT 196   // ceil(N/512) coarse dst buckets (dst>>9)
#define EPB1 8192  // edges per block in coarse passes
#define NBLK1 196  // ceil(E/EPB1)

typedef __attribute__((ext_vector_type(8))) short bf16x8;
typedef __attribute__((ext_vector_type(4))) float f32x4;
typedef __attribute__((ext_vector_type(2))) float f32x2;

__device__ __forceinline__ ushort f2bf(float f) {
    unsigned u = __float_as_uint(f);
    unsigned r = (u + 0x7fffu + ((u >> 16) & 1u)) >> 16;  // RNE
    return (ushort)r;
}
__device__ __forceinline__ float bflo(unsigned p) { return __uint_as_float(p << 16); }
__device__ __forceinline__ float bfhi(unsigned p) { return __uint_as_float(p & 0xffff0000u); }

// ---------------- CSR build via 2-level counting sort ----------------

__global__ __launch_bounds__(256) void k_p1(const int* __restrict__ dst, int* __restrict__ counts, int E) {
    __shared__ int h[NBKT];
    int t = threadIdx.x;
    for (int i = t; i < NBKT; i += 256) h[i] = 0;
    __syncthreads();
    int base = blockIdx.x * EPB1;
    for (int i = 0; i < EPB1; i += 256) {
        int e = base + i + t;
        if (e < E) atomicAdd(&h[dst[e] >> 9], 1);
    }
    __syncthreads();
    for (int i = t; i < NBKT; i += 256) counts[blockIdx.x * NBKT + i] = h[i];
}

__global__ __launch_bounds__(256) void k_p2(const int* __restrict__ counts, int* __restrict__ offs,
                                            int* __restrict__ bbase, int* __restrict__ rowptr, int E) {
    __shared__ int s[256];
    int t = threadIdx.x;
    int tot = 0;
    if (t < NBKT) {
        for (int blk = 0; blk < NBLK1; blk++) tot += counts[blk * NBKT + t];
    }
    s[t] = (t < NBKT) ? tot : 0;
    __syncthreads();
    for (int off = 1; off < 256; off <<= 1) {
        int v = (t >= off) ? s[t - off] : 0;
        __syncthreads();
        s[t] += v;
        __syncthreads();
    }
    int base = s[t] - tot;  // exclusive
    if (t < NBKT) {
        bbase[t] = base;
        int run = base;
        for (int blk = 0; blk < NBLK1; blk++) {
            int c = counts[blk * NBKT + t];
            offs[blk * NBKT + t] = run;
            run += c;
        }
    }
    if (t == 0) rowptr[N_NODES] = E;
}

__global__ __launch_bounds__(256) void k_p3(const int* __restrict__ src, const int* __restrict__ dst,
                                            const int* __restrict__ offs, int* __restrict__ ebuf, int E) {
    __shared__ int cur[NBKT];
    int t = threadIdx.x;
    for (int i = t; i < NBKT; i += 256) cur[i] = offs[blockIdx.x * NBKT + i];
    __syncthreads();
    int base = blockIdx.x * EPB1;
    for (int i = 0; i < EPB1; i += 256) {
        int e = base + i + t;
        if (e < E) {
            int d = dst[e], sv = src[e];
            int pos = atomicAdd(&cur[d >> 9], 1);
            ebuf[pos] = sv | ((d & 511) << 17);
        }
    }
}

__global__ __launch_bounds__(256) void k_p4(const int* __restrict__ ebuf, const int* __restrict__ bbase,
                                            int* __restrict__ rowptr, int* __restrict__ esrc, int E, int N) {
    __shared__ int fh[512], fex[512], fcur[512];
    __shared__ int sc[256];
    int t = threadIdx.x;
    int b = blockIdx.x;
    int base = bbase[b];
    int end = (b + 1 < NBKT) ? bbase[b + 1] : E;
    int cnt = end - base;
    fh[t] = 0; fh[t + 256] = 0; fcur[t] = 0; fcur[t + 256] = 0;
    __syncthreads();
    for (int i = t; i < cnt; i += 256) atomicAdd(&fh[(ebuf[base + i] >> 17) & 511], 1);
    __syncthreads();
    int a0 = fh[2 * t], a1 = fh[2 * t + 1];
    sc[t] = a0 + a1;
    __syncthreads();
    for (int off = 1; off < 256; off <<= 1) {
        int v = (t >= off) ? sc[t - off] : 0;
        __syncthreads();
        sc[t] += v;
        __syncthreads();
    }
    int ex = sc[t] - (a0 + a1);
    fex[2 * t] = ex;
    fex[2 * t + 1] = ex + a0;
    __syncthreads();
    int node0 = b << 9;
    for (int f = t; f < 512; f += 256) {
        int node = node0 + f;
        if (node < N) rowptr[node] = base + fex[f];
    }
    for (int i = t; i < cnt; i += 256) {
        int p = ebuf[base + i];
        int f = (p >> 17) & 511;
        int pos = base + fex[f] + atomicAdd(&fcur[f], 1);
        esrc[pos] = p & 0x1ffff;
    }
}

// ---------------- casts ----------------

__global__ __launch_bounds__(256) void k_cast_x(const float* __restrict__ x, ushort* __restrict__ xb, int NP) {
    int idx = blockIdx.x * 256 + threadIdx.x;
    if (idx >= NP * (KP0 / 8)) return;
    int row = idx / (KP0 / 8), j = idx % (KP0 / 8);
    int c0 = j * 8;
    ushort pk[8];
#pragma unroll
    for (int i = 0; i < 8; i++) {
        int c = c0 + i;
        float v = (row < N_NODES && c < F_IN) ? x[(size_t)row * F_IN + c] : 0.f;
        pk[i] = f2bf(v);
    }
    *(uint4*)(xb + (size_t)row * KP0 + c0) = *(uint4*)pk;
}

// fused weight cast: Wb0 [256][192] then Wb12 [2][256][128]
__global__ __launch_bounds__(256) void k_cast_w(
    const float* __restrict__ Wl0, const float* __restrict__ Wr0,
    const float* __restrict__ Wl, const float* __restrict__ Wr,
    short* __restrict__ Wb0, short* __restrict__ Wb12)
{
    int idx = blockIdx.x * 256 + threadIdx.x;
    if (idx < 256 * KP0) {
        int row = idx / KP0, col = idx % KP0;
        const float* W = (row < 128) ? Wl0 : Wr0;
        float v = (col < F_IN) ? W[(size_t)(row & 127) * F_IN + col] : 0.f;
        Wb0[idx] = (short)f2bf(v);
    } else {
        int i2 = idx - 256 * KP0;
        if (i2 >= 2 * 256 * HID) return;
        int layer = i2 / (256 * HID);
        int rem = i2 % (256 * HID);
        int row = rem / HID, col = rem % HID;
        const float* W = (row < 128) ? Wl : Wr;
        float v = W[(size_t)layer * HID * HID + (size_t)(row & 127) * HID + col];
        Wb12[i2] = (short)f2bf(v);
    }
}

// ---------------- register-tiled MFMA dual GEMM ----------------
// A bf16 [Mpad][KPV], W bf16 [256][KPV]
// Y (cols 0..127) stored fp8 e4m3: Yq[node][128]  (1 B/elem)
// R (cols 128..255) stored bf16 row-major [node][128]
template <int KPV>
__global__ __launch_bounds__(256) void k_gemm_rt(
    const short* __restrict__ A, const short* __restrict__ W,
    unsigned char* __restrict__ Yq, ushort* __restrict__ Rb, int M)
{
    constexpr int NK = KPV / 32;
    int wave = threadIdx.x >> 6;
    int lane = threadIdx.x & 63;
    int lr = lane & 15;
    int kg = lane >> 4;
    int m0 = blockIdx.x * 64;
    int wc = wave * 64;

    f32x4 acc[4][4];
#pragma unroll
    for (int i = 0; i < 4; i++)
#pragma unroll
        for (int j = 0; j < 4; j++) acc[i][j] = {0.f, 0.f, 0.f, 0.f};

    const short* abase = A + (size_t)(m0 + lr) * KPV + kg * 8;
    const short* wbase = W + (size_t)(wc + lr) * KPV + kg * 8;

#pragma unroll
    for (int ks = 0; ks < NK; ks++) {
        bf16x8 a[4], b[4];
#pragma unroll
        for (int rt = 0; rt < 4; rt++)
            a[rt] = *(const bf16x8*)(abase + (size_t)rt * 16 * KPV + ks * 32);
#pragma unroll
        for (int ntl = 0; ntl < 4; ntl++)
            b[ntl] = *(const bf16x8*)(wbase + (size_t)ntl * 16 * KPV + ks * 32);
#pragma unroll
        for (int rt = 0; rt < 4; rt++)
#pragma unroll
            for (int ntl = 0; ntl < 4; ntl++)
                acc[rt][ntl] = __builtin_amdgcn_mfma_f32_16x16x32_bf16(a[rt], b[ntl], acc[rt][ntl], 0, 0, 0);
    }

#pragma unroll
    for (int rt = 0; rt < 4; rt++) {
#pragma unroll
        for (int ntl = 0; ntl < 4; ntl++) {
            int c = wc + ntl * 16 + lr;      // wave-uniform Y/R split (wc 0,64 -> Y; 128,192 -> R)
            bool isY = (c < HID);
#pragma unroll
            for (int r = 0; r < 4; r++) {
                float v = acc[rt][ntl][r];
                float vp = __shfl_xor(v, 1);
                int node = m0 + rt * 16 + kg * 4 + r;
                if (isY) {
                    // bytes (c,c+1) on this lane pair; (c+2,c+3) from partner pair
                    int b01 = __builtin_amdgcn_cvt_pk_fp8_f32(v, vp, 0, false);
                    int b23 = __shfl_xor(b01, 2);
                    if (!(lr & 3) && node < M) {
                        unsigned pk = ((unsigned)b01 & 0xffffu) | ((unsigned)b23 << 16);
                        *(unsigned*)(Yq + (size_t)node * HID + c) = pk;
                    }
                } else {
                    unsigned pk = (unsigned)f2bf(v) | ((unsigned)f2bf(vp) << 16);
                    if (!(lr & 1) && node < M)
                        *(unsigned*)(Rb + (size_t)node * HID + (c - HID)) = pk;
                }
            }
        }
    }
}

// ---------------- fused aggregate + bias + root + (LN) + ReLU (+ final proj) ----------------
// one wave per node; half-wave per edge (32 lanes x 4B = 128 B fp8 row).
// lane owns features 4c..4c+3 (c = lane&31).
// Slim inner loop: pre-scaled ids (byte offsets via shfl), 32-bit saddr loads,
// unmasked full 8-edge groups + one masked partial group, float2 packed accumulate.
__global__ __launch_bounds__(256) void k_aggregate(
    const unsigned char* __restrict__ Yq, const ushort* __restrict__ Rm,
    const ushort* __restrict__ Hres,
    const int* __restrict__ rowptr, const int* __restrict__ esrc,
    const float* __restrict__ bias, ushort* __restrict__ HbOut,
    const float* __restrict__ lW, const float* __restrict__ lb,
    float* __restrict__ out, int N, int mode)
{
    int lane = threadIdx.x & 63;
    int node = blockIdx.x * 4 + (threadIdx.x >> 6);
    if (node >= N) return;
    int h = lane >> 5;
    unsigned c = lane & 31;
    unsigned c4 = c * 4u;
    int beg = rowptr[node], end = rowptr[node + 1];
    f32x2 a01 = {0.f, 0.f}, a23 = {0.f, 0.f};
    for (int c0 = beg; c0 < end; c0 += 64) {
        int lim = end - c0; if (lim > 64) lim = 64;
        int idv = (c0 + lane < end) ? esrc[c0 + lane] : 0;
        int ids7 = idv << 7;                       // byte offset of row
        int nfull = lim & ~7;
        int t = 0;
        for (; t < nfull; t += 8) {                // unmasked: 4 loads in flight/lane
            unsigned q[4];
#pragma unroll
            for (int u = 0; u < 4; u++) {
                unsigned off = (unsigned)__shfl(ids7, t + 2 * u + h) + c4;
                q[u] = *(const unsigned*)(Yq + off);
            }
#pragma unroll
            for (int u = 0; u < 4; u++) {
                a01 += __builtin_amdgcn_cvt_pk_f32_fp8((int)q[u], false);
                a23 += __builtin_amdgcn_cvt_pk_f32_fp8((int)q[u], true);
            }
        }
        if (t < lim) {                             // single masked partial group
            unsigned q[4];
#pragma unroll
            for (int u = 0; u < 4; u++) {
                int e = t + 2 * u + h;
                unsigned off = (unsigned)__shfl(ids7, e & 63) + c4;
                unsigned qq = *(const unsigned*)(Yq + off);
                q[u] = (e < lim) ? qq : 0u;        // 0x00 decodes to +0.0 in e4m3
            }
#pragma unroll
            for (int u = 0; u < 4; u++) {
                a01 += __builtin_amdgcn_cvt_pk_f32_fp8((int)q[u], false);
                a23 += __builtin_amdgcn_cvt_pk_f32_fp8((int)q[u], true);
            }
        }
    }
    float s0 = a01[0], s1 = a01[1], s2 = a23[0], s3 = a23[1];
    // merge halves: both halves get full sums (features duplicated across halves)
    s0 += __shfl_xor(s0, 32); s1 += __shfl_xor(s1, 32);
    s2 += __shfl_xor(s2, 32); s3 += __shfl_xor(s3, 32);

    float inv = 1.0f / fmaxf((float)(end - beg), 1.0f);
    size_t base = (size_t)node * HID + 4 * c;
    float4 b4 = *(const float4*)(bias + 4 * c);
    uint2 r2 = *(const uint2*)(Rm + base);
    float v0 = s0 * inv + b4.x + bflo(r2.x);
    float v1 = s1 * inv + b4.y + bfhi(r2.x);
    float v2 = s2 * inv + b4.z + bflo(r2.y);
    float v3 = s3 * inv + b4.w + bfhi(r2.y);
    float o0, o1, o2, o3;
    if (mode == 0) {
        o0 = fmaxf(v0, 0.f); o1 = fmaxf(v1, 0.f);
        o2 = fmaxf(v2, 0.f); o3 = fmaxf(v3, 0.f);
    } else {
        uint2 h2 = *(const uint2*)(Hres + base);
        float z0 = v0 + bflo(h2.x), z1 = v1 + bfhi(h2.x);
        float z2 = v2 + bflo(h2.y), z3 = v3 + bfhi(h2.y);
        float sum = z0 + z1 + z2 + z3;
#pragma unroll
        for (int off = 16; off; off >>= 1) sum += __shfl_xor(sum, off);  // 5-level: within half
        float mu = sum * (1.f / 128.f);
        float d0 = z0 - mu, d1 = z1 - mu, d2 = z2 - mu, d3 = z3 - mu;
        float vs = d0 * d0 + d1 * d1 + d2 * d2 + d3 * d3;
#pragma unroll
        for (int off = 16; off; off >>= 1) vs += __shfl_xor(vs, off);
        float rstd = rsqrtf(vs * (1.f / 128.f) + 1e-5f);
        o0 = fmaxf(d0 * rstd, 0.f); o1 = fmaxf(d1 * rstd, 0.f);
        o2 = fmaxf(d2 * rstd, 0.f); o3 = fmaxf(d3 * rstd, 0.f);
    }
    if (mode == 2) {
        float4 w0 = *(const float4*)(lW + 4 * c);
        float4 w1 = *(const float4*)(lW + 128 + 4 * c);
        float p0 = o0 * w0.x + o1 * w0.y + o2 * w0.z + o3 * w0.w;
        float p1 = o0 * w1.x + o1 * w1.y + o2 * w1.z + o3 * w1.w;
#pragma unroll
        for (int off = 16; off; off >>= 1) {       // 5-level: full dot within half
            p0 += __shfl_xor(p0, off);
            p1 += __shfl_xor(p1, off);
        }
        if (lane == 0) {
            out[(size_t)node * 2 + 0] = p0 + lb[0];
            out[(size_t)node * 2 + 1] = p1 + lb[1];
        }
    } else if (h == 0) {
        unsigned pk0 = (unsigned)f2bf(o0) | ((unsigned)f2bf(o1) << 16);
        unsigned pk1 = (unsigned)f2bf(o2) | ((unsigned)f2bf(o3) << 16);
        uint2 pk; pk.x = pk0; pk.y = pk1;
        *(uint2*)(HbOut + base) = pk;
    }
}

extern "C" void kernel_launch(void* const* d_in, const int* in_sizes, int n_in,
                              void* d_out, int out_size, void* d_ws, size_t ws_size,
                              hipStream_t stream) {
    const int N = N_NODES, E = N_EDGES;
    const float* x   = (const float*)d_in[0];
    const int*   ei  = (const int*)d_in[1];
    const float* Wl0 = (const float*)d_in[2];
    const float* bl0 = (const float*)d_in[3];
    const float* Wr0 = (const float*)d_in[4];
    const float* Wl  = (const float*)d_in[5];
    const float* bl  = (const float*)d_in[6];
    const float* Wr  = (const float*)d_in[7];
    const float* lW  = (const float*)d_in[8];
    const float* lb  = (const float*)d_in[9];
    float* out = (float*)d_out;

    const int* src = ei;
    const int* dst = ei + E;

    const int PADR = 64;
    const int NP = ((N + 63) / 64) * 64;

    char* w = (char*)d_ws;
    unsigned char* Yq = (unsigned char*)w; w += (size_t)(N + PADR) * HID;  // fp8
    ushort* Rb  = (ushort*)w; w += (size_t)(N + PADR) * HID * sizeof(ushort);
    ushort* Hb  = (ushort*)w; w += (size_t)(N + PADR) * HID * sizeof(ushort);
    ushort* xb  = (ushort*)w; w += (size_t)(N + PADR) * KP0 * sizeof(ushort);
    short*  Wb0 = (short*)w;  w += (size_t)256 * KP0 * sizeof(short);
    short*  Wb12= (short*)w;  w += (size_t)2 * 256 * HID * sizeof(short);
    int* counts = (int*)w;    w += (size_t)NBLK1 * NBKT * sizeof(int);
    int* offs   = (int*)w;    w += (size_t)NBLK1 * NBKT * sizeof(int);
    int* bbase  = (int*)w;    w += (size_t)NBKT * sizeof(int);
    int* rowptr = (int*)w;    w += (size_t)(N + 1) * sizeof(int);
    int* ebuf   = (int*)w;    w += (size_t)E * sizeof(int);
    int* esrc   = (int*)w;    w += (size_t)E * sizeof(int);

    const int nbGemm = (N + 63) / 64;
    const int nbNode = (N + 3) / 4;

    // CSR build (2-level counting sort)
    k_p1<<<NBLK1, 256, 0, stream>>>(dst, counts, E);
    k_p2<<<1, 256, 0, stream>>>(counts, offs, bbase, rowptr, E);
    k_p3<<<NBLK1, 256, 0, stream>>>(src, dst, offs, ebuf, E);
    k_p4<<<NBKT, 256, 0, stream>>>(ebuf, bbase, rowptr, esrc, E, N);

    // casts
    k_cast_x<<<(NP * (KP0 / 8) + 255) / 256, 256, 0, stream>>>(x, xb, NP);
    k_cast_w<<<(256 * KP0 + 2 * 256 * HID + 255) / 256, 256, 0, stream>>>(Wl0, Wr0, Wl, Wr, Wb0, Wb12);

    // layer 0
    k_gemm_rt<KP0><<<nbGemm, 256, 0, stream>>>((const short*)xb, Wb0, Yq, Rb, N);
    k_aggregate<<<nbNode, 256, 0, stream>>>(Yq, Rb, nullptr, rowptr, esrc, bl0, Hb,
                                            nullptr, nullptr, nullptr, N, 0);

    // layer 1
    k_gemm_rt<HID><<<nbGemm, 256, 0, stream>>>((const short*)Hb, Wb12, Yq, Rb, N);
    k_aggregate<<<nbNode, 256, 0, stream>>>(Yq, Rb, Hb, rowptr, esrc, bl, Hb,
                                            nullptr, nullptr, nullptr, N, 1);

    // layer 2 + fused final projection
    k_gemm_rt<HID><<<nbGemm, 256, 0, stream>>>((const short*)Hb, Wb12 + 256 * HID, Yq, Rb, N);
    k_aggregate<<<nbNode, 256, 0, stream>>>(Yq, Rb, Hb, rowptr, esrc, bl + HID, nullptr,
                                            lW, lb, out, N, 2);
}